// Round 5
// baseline (506.383 us; speedup 1.0000x reference)
//
#include <hip/hip_runtime.h>

#define B_ 32
#define C_ 512
#define HW_ 3136
#define KF_ 512
#define KM_ 48
#define NCL_ 5

typedef __attribute__((ext_vector_type(8))) short short8;
typedef __attribute__((ext_vector_type(4))) short short4v;
typedef __attribute__((ext_vector_type(4))) float floatx4;
typedef unsigned int u32;
typedef u32 __attribute__((address_space(1))) gu32;
typedef u32 __attribute__((address_space(3))) lu32;

__device__ __forceinline__ unsigned short f2bf(float f) {
    union { float f; unsigned u; } v; v.f = f;
    unsigned r = v.u + 0x7FFFu + ((v.u >> 16) & 1u);
    return (unsigned short)(r >> 16);
}
__device__ __forceinline__ float bf2f(unsigned short u) {
    union { unsigned u; float f; } v; v.u = ((unsigned)u) << 16;
    return v.f;
}
__device__ __forceinline__ void gl2lds16(const unsigned short* g, unsigned short* l) {
    __builtin_amdgcn_global_load_lds((const gu32*)g, (lu32*)l, 16, 0, 0);
}

// ---- K0: normalize conv weights -> bf16 wn; clutter -> ck (clip + L1 norm)
__global__ __launch_bounds__(64) void prep_kernel(const float* __restrict__ w,
                                                  const float* __restrict__ cl,
                                                  unsigned short* __restrict__ wn,
                                                  float* __restrict__ ck) {
    int bid = blockIdx.x, t = threadIdx.x;
    if (bid < KF_) {
        const float* row = w + (size_t)bid * C_;
        float ss = 0.f;
        float x[8];
#pragma unroll
        for (int j = 0; j < 8; ++j) { x[j] = row[t * 8 + j]; ss += x[j] * x[j]; }
        for (int m = 32; m >= 1; m >>= 1) ss += __shfl_xor(ss, m);
        float inv = 1.f / sqrtf(ss);
#pragma unroll
        for (int j = 0; j < 8; ++j) wn[(size_t)bid * C_ + t * 8 + j] = f2bf(x[j] * inv);
    } else {
        int n = bid - KF_;
        if (n >= NCL_) return;
        const float* row = cl + (size_t)n * KF_;
        float s = 0.f;
        float v[8];
#pragma unroll
        for (int j = 0; j < 8; ++j) {
            float x = row[t * 8 + j];
            x = fminf(fmaxf(x, 0.f), 1.f);
            v[j] = x; s += x;
        }
        for (int m = 32; m >= 1; m >>= 1) s += __shfl_xor(s, m);
        float inv = 1.f / fmaxf(s, 1e-12f);
#pragma unroll
        for (int j = 0; j < 8; ++j) ck[(size_t)n * KF_ + t * 8 + j] = v[j] * inv;
    }
}

// ---- K1: streaming pass: vgg -> xnt (raw bf16, [b*HW+p][c]), invn, vgg copy
__global__ __launch_bounds__(512) void xprep_kernel(const float* __restrict__ vgg,
                                                    unsigned short* __restrict__ xnt,
                                                    float* __restrict__ invn,
                                                    float* __restrict__ out_vgg,
                                                    int write_vgg) {
    int pt = blockIdx.x, b = blockIdx.y;
    int tid = threadIdx.x;
    int px = tid & 63, cq = tid >> 6;
    __shared__ __align__(16) unsigned short tile[64][512];
    __shared__ float ssp[8][64];
    const float* vcol = vgg + (size_t)b * C_ * HW_ + pt * 64 + px;
    float* ovcol = out_vgg + (size_t)b * C_ * HW_ + pt * 64 + px;

    float ss = 0.f;
#pragma unroll
    for (int j = 0; j < 16; ++j) {
        int c0 = cq * 64 + j * 4;
        float x0 = vcol[(size_t)(c0 + 0) * HW_];
        float x1 = vcol[(size_t)(c0 + 1) * HW_];
        float x2 = vcol[(size_t)(c0 + 2) * HW_];
        float x3 = vcol[(size_t)(c0 + 3) * HW_];
        ss += x0 * x0 + x1 * x1 + x2 * x2 + x3 * x3;
        short4v pk;
        pk[0] = (short)f2bf(x0); pk[1] = (short)f2bf(x1);
        pk[2] = (short)f2bf(x2); pk[3] = (short)f2bf(x3);
        *(short4v*)&tile[px][c0] = pk;
        if (write_vgg) {
            ovcol[(size_t)(c0 + 0) * HW_] = x0;
            ovcol[(size_t)(c0 + 1) * HW_] = x1;
            ovcol[(size_t)(c0 + 2) * HW_] = x2;
            ovcol[(size_t)(c0 + 3) * HW_] = x3;
        }
    }
    ssp[cq][px] = ss;
    __syncthreads();
    if (tid < 64) {
        float s = 0.f;
#pragma unroll
        for (int q = 0; q < 8; ++q) s += ssp[q][tid];
        float n = sqrtf(s);
        invn[(size_t)b * HW_ + pt * 64 + tid] = (n == 0.f) ? 1.f : 1.f / n;
    }
    __syncthreads();
    int row = tid >> 3, ch = tid & 7;
    unsigned short* orow = xnt + ((size_t)b * HW_ + pt * 64 + row) * 512;
#pragma unroll
    for (int j = 0; j < 8; ++j) {
        int c8 = (ch + 8 * j) * 8;
        *(short8*)(orow + c8) = *(const short8*)&tile[row][c8];
    }
}

// ---- K2: flat GEMM act = exp(30 * (xnt . wn) * invn) + bg partials
// act written in 16k CHUNKS: act_c[(ch*100352 + row)*16 + kin], ch = f>>4.
__global__ __launch_bounds__(256) void gemm_act_kernel(const unsigned short* __restrict__ xnt,
                                                       const unsigned short* __restrict__ wn,
                                                       const float* __restrict__ invn,
                                                       const float* __restrict__ ck,
                                                       unsigned short* __restrict__ act,
                                                       float* __restrict__ bgacc) {
    int pt = blockIdx.x, ft = blockIdx.y;
    int tid = threadIdx.x, lane = tid & 63, w = tid >> 6;
    int wm = w & 1, wq = w >> 1;
    __shared__ __align__(16) unsigned short a_lds[128 * 64];
    __shared__ __align__(16) unsigned short b_lds[128 * 64];
    __shared__ float ck_l[NCL_ * KF_];
    __shared__ float inv_l[128];
    __shared__ float bga_l[128 * NCL_];

    for (int i = tid; i < NCL_ * KF_; i += 256) ck_l[i] = ck[i];
    if (tid < 128) inv_l[tid] = invn[(size_t)pt * 128 + tid];
    for (int i = tid; i < 128 * NCL_; i += 256) bga_l[i] = 0.f;

    const unsigned short* ga = wn + ((size_t)(ft * 128) + (tid >> 3)) * 512 + (tid & 7) * 8;
    const unsigned short* gb = xnt + ((size_t)pt * 128 + (tid >> 3)) * 512 + (tid & 7) * 8;
    unsigned short* la = a_lds + (tid >> 3) * 64 + (tid & 7) * 8;
    unsigned short* lb = b_lds + (tid >> 3) * 64 + (tid & 7) * 8;

    floatx4 acc[4][4] = {};
    for (int ks = 0; ks < 8; ++ks) {
#pragma unroll
        for (int s = 0; s < 4; ++s) {
            gl2lds16(ga + (size_t)s * 32 * 512 + ks * 64, la + s * 32 * 64);
            gl2lds16(gb + (size_t)s * 32 * 512 + ks * 64, lb + s * 32 * 64);
        }
        __syncthreads();
#pragma unroll
        for (int k2 = 0; k2 < 2; ++k2) {
            short8 af[4], bf[4];
#pragma unroll
            for (int i = 0; i < 4; ++i) {
                af[i] = *(const short8*)&a_lds[(wm * 64 + i * 16 + (lane & 15)) * 64 + k2 * 32 + (lane >> 4) * 8];
                bf[i] = *(const short8*)&b_lds[(wq * 64 + i * 16 + (lane & 15)) * 64 + k2 * 32 + (lane >> 4) * 8];
            }
#pragma unroll
            for (int mi = 0; mi < 4; ++mi)
#pragma unroll
                for (int ni = 0; ni < 4; ++ni)
                    acc[mi][ni] = __builtin_amdgcn_mfma_f32_16x16x32_bf16(af[mi], bf[ni], acc[mi][ni], 0, 0, 0);
        }
        __syncthreads();
    }

#pragma unroll
    for (int ni = 0; ni < 4; ++ni) {
        int px_l = wq * 64 + ni * 16 + (lane & 15);
        float inv = inv_l[px_l];
        size_t row_g = (size_t)pt * 128 + px_l;
        float bp[NCL_] = {0.f, 0.f, 0.f, 0.f, 0.f};
#pragma unroll
        for (int mi = 0; mi < 4; ++mi) {
            int f_g = ft * 128 + wm * 64 + mi * 16 + (lane >> 4) * 4;
            int chn = ft * 8 + wm * 4 + mi;      // f_g >> 4
            int kin = (lane >> 4) * 4;           // within 16k chunk
            short4v pk;
            float av[4];
#pragma unroll
            for (int r = 0; r < 4; ++r) {
                float cv = acc[mi][ni][r] * inv;
                float a = cv > 0.f ? __expf(30.f * cv) : 0.f;
                av[r] = a;
                pk[r] = (short)f2bf(a);
            }
            *(short4v*)(act + ((size_t)chn * 100352 + row_g) * 16 + kin) = pk;
#pragma unroll
            for (int n = 0; n < NCL_; ++n)
                bp[n] += av[0] * ck_l[n * KF_ + f_g] + av[1] * ck_l[n * KF_ + f_g + 1] +
                         av[2] * ck_l[n * KF_ + f_g + 2] + av[3] * ck_l[n * KF_ + f_g + 3];
        }
#pragma unroll
        for (int n = 0; n < NCL_; ++n) {
            float v = bp[n];
            v += __shfl_xor(v, 16);
            v += __shfl_xor(v, 32);
            if ((lane >> 4) == 0) atomicAdd(&bga_l[px_l * NCL_ + n], v);
        }
    }
    __syncthreads();
    if (tid < 128) {
        size_t row_g = (size_t)pt * 128 + tid;
#pragma unroll
        for (int n = 0; n < NCL_; ++n)
            atomicAdd(&bgacc[row_g * 8 + n], bga_l[tid * NCL_ + n]);
    }
}

// ---- K4: single-pass fg, 1024 threads (16 waves, 1 px/wave), 16k chunks.
// Per-chunk per-thread loads: 12 mm dwords + 1 act short8 (register-light so
// the compiler keeps the prefetch hoisted). K=32 MFMA fed by 2-chunk parity.
__global__ __launch_bounds__(1024) void fg_kernel(const unsigned short* __restrict__ act,
                                                  const float* __restrict__ mm,
                                                  const float* __restrict__ bgacc,
                                                  float* __restrict__ pm) {
    int p0 = blockIdx.x * 16;
    int tid = threadIdx.x;
    int lane = tid & 63, pp = tid >> 6;   // wave id = pixel
    int li = lane & 15, q = lane >> 4;

    __shared__ __align__(16) unsigned short actl[16 * 578];  // [px][b*18 + k]
    __shared__ __align__(16) unsigned short mml[16 * 866];   // [px][m*18 + k]
    __shared__ float csum_s[48 * 16];   // [m][px]
    __shared__ float pms[48 * 32];      // [m][b]
    __shared__ float bgs[32 * 16];      // [b][px]

    if (tid < 768) csum_s[tid] = 0.f;
    if (tid < 512) {
        int b = tid >> 4, px = tid & 15;
        const float* bga = bgacc + ((size_t)b * HW_ + p0 + px) * 8;
        float mx = -1e30f;
#pragma unroll
        for (int n = 0; n < NCL_; ++n) mx = fmaxf(mx, logf(bga[n] * 0.6f + 1e-10f));
        bgs[tid] = mx;
    }
    {
        int i = tid;
        if (i < 1536) pms[i] = 0.f;
        i = tid + 1024;
        if (i < 1536) pms[i] = 0.f;
    }

    // staging roles
    int srow = tid >> 1, skh = tid & 1;            // act: row-in-tile, k-half
    int sab = srow >> 4, sap = srow & 15;          // b, px
    int mpx = tid & 15, mkq = (tid >> 4) & 3, mg = tid >> 6;  // mm: px, k-quad, m-group(3m)

    const unsigned short* agp = act + ((size_t)sab * HW_ + p0 + sap) * 16 + skh * 8;
    const float* mgp = mm + p0 + mpx;
    unsigned short* awr = &actl[sap * 578 + sab * 18 + skh * 8];
    unsigned short* mwr = &mml[mpx * 866 + mg * 3 * 18 + mkq * 4];

    float csp[3] = {0.f, 0.f, 0.f};
    short8 areg;
    float mr[3][4];
    short8 fa[2], fm[3];
    floatx4 acc[3][2] = {};

    // prologue: chunk 0
    areg = *(const short8*)agp;
#pragma unroll
    for (int j = 0; j < 3; ++j)
#pragma unroll
        for (int kk = 0; kk < 4; ++kk)
            mr[j][kk] = mgp[(size_t)((mg * 3 + j) * KF_ + mkq * 4 + kk) * HW_];

#pragma unroll 1
    for (int ch = 0; ch < 32; ++ch) {
        __syncthreads();
        // stage regs -> LDS
        *(short8*)awr = areg;
#pragma unroll
        for (int j = 0; j < 3; ++j) {
            short4v pk;
#pragma unroll
            for (int kk = 0; kk < 4; ++kk) {
                float x = fminf(fmaxf(mr[j][kk], 0.f), 1.f);
                csp[j] += x;
                pk[kk] = (short)f2bf(x);
            }
            *(short4v*)(mwr + j * 18) = pk;
        }
        __syncthreads();
        // prefetch next chunk (light: 12 dwords + 1 short8 per thread)
        if (ch < 31) {
            agp += (size_t)100352 * 16;
            areg = *(const short8*)agp;
            int kb = (ch + 1) * 16;
#pragma unroll
            for (int j = 0; j < 3; ++j)
#pragma unroll
                for (int kk = 0; kk < 4; ++kk)
                    mr[j][kk] = mgp[(size_t)((mg * 3 + j) * KF_ + kb + mkq * 4 + kk) * HW_];
        }
        // parity fragment reads into registers
        if ((q >> 1) == (ch & 1)) {
            int ko = (q & 1) * 8;
            fa[0] = *(const short8*)&actl[pp * 578 + li * 18 + ko];
            fa[1] = *(const short8*)&actl[pp * 578 + (16 + li) * 18 + ko];
            fm[0] = *(const short8*)&mml[pp * 866 + li * 18 + ko];
            fm[1] = *(const short8*)&mml[pp * 866 + (16 + li) * 18 + ko];
            fm[2] = *(const short8*)&mml[pp * 866 + (32 + li) * 18 + ko];
        }
        if (ch & 1) {
#pragma unroll
            for (int mf = 0; mf < 3; ++mf) {
                acc[mf][0] = __builtin_amdgcn_mfma_f32_16x16x32_bf16(fm[mf], fa[0], acc[mf][0], 0, 0, 0);
                acc[mf][1] = __builtin_amdgcn_mfma_f32_16x16x32_bf16(fm[mf], fa[1], acc[mf][1], 0, 0, 0);
            }
        }
    }

    // csum finalize (4 k-quad threads share each (m,px))
#pragma unroll
    for (int j = 0; j < 3; ++j)
        atomicAdd(&csum_s[(mg * 3 + j) * 16 + mpx], csp[j]);
    __syncthreads();

    // epilogue: log, bg-max, per-(m,b) pixel sum
#pragma unroll
    for (int mf = 0; mf < 3; ++mf)
#pragma unroll
        for (int bf = 0; bf < 2; ++bf) {
            int b = bf * 16 + li;
            float bgv = bgs[b * 16 + pp];
#pragma unroll
            for (int r = 0; r < 4; ++r) {
                int m = mf * 16 + q * 4 + r;
                float inv = 1.f / fmaxf(csum_s[m * 16 + pp], 1e-12f);
                float v = fmaxf(logf(acc[mf][bf][r] * inv * 0.4f + 1e-10f), bgv);
                atomicAdd(&pms[m * 32 + b], v);
            }
        }
    __syncthreads();
    if (tid < 512) {
        int i3 = tid * 3;
#pragma unroll
        for (int j = 0; j < 3; ++j) {
            int i = i3 + j;
            int m = i >> 5, b = i & 31;
            atomicAdd(&pm[(size_t)b * KM_ + m], pms[i]);
        }
    }
}

// ---- K5: scores -> mix_likeli -> softmax
__global__ __launch_bounds__(64) void final_kernel(const float* __restrict__ pm,
                                                   float* __restrict__ out_soft,
                                                   float* __restrict__ out_ml) {
    int b = threadIdx.x;
    if (b >= B_) return;
    float ml[12];
#pragma unroll
    for (int c = 0; c < 12; ++c) {
        float s = -1e30f;
#pragma unroll
        for (int j = 0; j < 4; ++j) s = fmaxf(s, pm[(size_t)b * KM_ + c * 4 + j]);
        ml[c] = s / (float)HW_;
    }
    float z[12], zs = 0.f;
#pragma unroll
    for (int c = 0; c < 12; ++c) {
        float e = fminf(fmaxf(ml[c] * 2.f, -88.7f), 88.7f);
        z[c] = expf(e); zs += z[c];
    }
#pragma unroll
    for (int c = 0; c < 12; ++c) {
        out_soft[(size_t)b * 12 + c] = z[c] / zs;
        out_ml[(size_t)b * 12 + c] = ml[c];
    }
}

extern "C" void kernel_launch(void* const* d_in, const int* in_sizes, int n_in,
                              void* d_out, int out_size, void* d_ws, size_t ws_size,
                              hipStream_t stream) {
    const float* vgg = (const float*)d_in[0];
    const float* cw  = (const float*)d_in[1];
    const float* mmp = (const float*)d_in[2];
    const float* cl  = (const float*)d_in[3];
    float* out = (float*)d_out;
    char* ws = (char*)d_ws;

    unsigned short* wn   = (unsigned short*)(ws);              // 524288 B
    float* ck            = (float*)(ws + 524288);              // 10240 B
    float* invn          = (float*)(ws + 534528);              // 401408 B
    float* pm            = (float*)(ws + 935936);              // 6144 B
    float* bgacc         = (float*)(ws + 942080);              // 3211264 B
    unsigned short* xnt  = (unsigned short*)(ws + 4153344);    // 102760448 B
    const size_t ACT_OFF = 4153344 + 102760448;                // 106913792
    const size_t ACT_BYTES = (size_t)B_ * HW_ * KF_ * 2;       // 102760448

    int big_ws = (ws_size >= ACT_OFF + ACT_BYTES) ? 1 : 0;
    unsigned short* act = big_ws ? (unsigned short*)(ws + ACT_OFF)
                                 : (unsigned short*)(out + 384);

    hipMemsetAsync(pm, 0, (size_t)B_ * KM_ * sizeof(float), stream);
    hipMemsetAsync(bgacc, 0, (size_t)B_ * HW_ * 8 * sizeof(float), stream);
    prep_kernel<<<dim3(KF_ + NCL_), dim3(64), 0, stream>>>(cw, cl, wn, ck);
    xprep_kernel<<<dim3(49, 32), dim3(512), 0, stream>>>(vgg, xnt, invn, out + 384, big_ws);
    gemm_act_kernel<<<dim3(784, 4), dim3(256), 0, stream>>>(xnt, wn, invn, ck, act, bgacc);
    fg_kernel<<<dim3(196), dim3(1024), 0, stream>>>(act, mmp, bgacc, pm);
    final_kernel<<<1, 64, 0, stream>>>(pm, out, out + 384 + (size_t)B_ * C_ * HW_);
    if (!big_ws)
        hipMemcpyAsync(out + 384, vgg, (size_t)B_ * C_ * HW_ * sizeof(float),
                       hipMemcpyDeviceToDevice, stream);
}

// Round 6
// 469.688 us; speedup vs baseline: 1.0781x; 1.0781x over previous
//
#include <hip/hip_runtime.h>

#define B_ 32
#define C_ 512
#define HW_ 3136
#define KF_ 512
#define KM_ 48
#define NCL_ 5

typedef __attribute__((ext_vector_type(8))) short short8;
typedef __attribute__((ext_vector_type(4))) short short4v;
typedef __attribute__((ext_vector_type(4))) float floatx4;
typedef unsigned int u32;
typedef u32 __attribute__((address_space(1))) gu32;
typedef u32 __attribute__((address_space(3))) lu32;

__device__ __forceinline__ unsigned short f2bf(float f) {
    union { float f; unsigned u; } v; v.f = f;
    unsigned r = v.u + 0x7FFFu + ((v.u >> 16) & 1u);
    return (unsigned short)(r >> 16);
}
__device__ __forceinline__ float bf2f(unsigned short u) {
    union { unsigned u; float f; } v; v.u = ((unsigned)u) << 16;
    return v.f;
}
__device__ __forceinline__ void gl2lds16(const void* g, void* l) {
    __builtin_amdgcn_global_load_lds((const gu32*)g, (lu32*)l, 16, 0, 0);
}
__device__ __forceinline__ void gl2lds4(const void* g, void* l) {
    __builtin_amdgcn_global_load_lds((const gu32*)g, (lu32*)l, 4, 0, 0);
}

// ---- K0: normalize conv weights -> bf16 wn; clutter -> ck (clip + L1 norm)
__global__ __launch_bounds__(64) void prep_kernel(const float* __restrict__ w,
                                                  const float* __restrict__ cl,
                                                  unsigned short* __restrict__ wn,
                                                  float* __restrict__ ck) {
    int bid = blockIdx.x, t = threadIdx.x;
    if (bid < KF_) {
        const float* row = w + (size_t)bid * C_;
        float ss = 0.f;
        float x[8];
#pragma unroll
        for (int j = 0; j < 8; ++j) { x[j] = row[t * 8 + j]; ss += x[j] * x[j]; }
        for (int m = 32; m >= 1; m >>= 1) ss += __shfl_xor(ss, m);
        float inv = 1.f / sqrtf(ss);
#pragma unroll
        for (int j = 0; j < 8; ++j) wn[(size_t)bid * C_ + t * 8 + j] = f2bf(x[j] * inv);
    } else {
        int n = bid - KF_;
        if (n >= NCL_) return;
        const float* row = cl + (size_t)n * KF_;
        float s = 0.f;
        float v[8];
#pragma unroll
        for (int j = 0; j < 8; ++j) {
            float x = row[t * 8 + j];
            x = fminf(fmaxf(x, 0.f), 1.f);
            v[j] = x; s += x;
        }
        for (int m = 32; m >= 1; m >>= 1) s += __shfl_xor(s, m);
        float inv = 1.f / fmaxf(s, 1e-12f);
#pragma unroll
        for (int j = 0; j < 8; ++j) ck[(size_t)n * KF_ + t * 8 + j] = v[j] * inv;
    }
}

// ---- K1: streaming pass: vgg -> xnt (raw bf16, [b*HW+p][c]), invn, vgg copy
__global__ __launch_bounds__(512) void xprep_kernel(const float* __restrict__ vgg,
                                                    unsigned short* __restrict__ xnt,
                                                    float* __restrict__ invn,
                                                    float* __restrict__ out_vgg,
                                                    int write_vgg) {
    int pt = blockIdx.x, b = blockIdx.y;
    int tid = threadIdx.x;
    int px = tid & 63, cq = tid >> 6;
    __shared__ __align__(16) unsigned short tile[64][512];
    __shared__ float ssp[8][64];
    const float* vcol = vgg + (size_t)b * C_ * HW_ + pt * 64 + px;
    float* ovcol = out_vgg + (size_t)b * C_ * HW_ + pt * 64 + px;

    float ss = 0.f;
#pragma unroll
    for (int j = 0; j < 16; ++j) {
        int c0 = cq * 64 + j * 4;
        float x0 = vcol[(size_t)(c0 + 0) * HW_];
        float x1 = vcol[(size_t)(c0 + 1) * HW_];
        float x2 = vcol[(size_t)(c0 + 2) * HW_];
        float x3 = vcol[(size_t)(c0 + 3) * HW_];
        ss += x0 * x0 + x1 * x1 + x2 * x2 + x3 * x3;
        short4v pk;
        pk[0] = (short)f2bf(x0); pk[1] = (short)f2bf(x1);
        pk[2] = (short)f2bf(x2); pk[3] = (short)f2bf(x3);
        *(short4v*)&tile[px][c0] = pk;
        if (write_vgg) {
            ovcol[(size_t)(c0 + 0) * HW_] = x0;
            ovcol[(size_t)(c0 + 1) * HW_] = x1;
            ovcol[(size_t)(c0 + 2) * HW_] = x2;
            ovcol[(size_t)(c0 + 3) * HW_] = x3;
        }
    }
    ssp[cq][px] = ss;
    __syncthreads();
    if (tid < 64) {
        float s = 0.f;
#pragma unroll
        for (int q = 0; q < 8; ++q) s += ssp[q][tid];
        float n = sqrtf(s);
        invn[(size_t)b * HW_ + pt * 64 + tid] = (n == 0.f) ? 1.f : 1.f / n;
    }
    __syncthreads();
    int row = tid >> 3, ch = tid & 7;
    unsigned short* orow = xnt + ((size_t)b * HW_ + pt * 64 + row) * 512;
#pragma unroll
    for (int j = 0; j < 8; ++j) {
        int c8 = (ch + 8 * j) * 8;
        *(short8*)(orow + c8) = *(const short8*)&tile[row][c8];
    }
}

// ---- K2: flat GEMM act = exp(30 * (xnt . wn) * invn) + bg partials
// act written in 16k CHUNKS: act_c[(ch*100352 + row)*16 + kin], ch = f>>4.
// grid (4 ft, 784 pt): ft fastest so same-pt blocks share xnt tile in L2/L3.
__global__ __launch_bounds__(256) void gemm_act_kernel(const unsigned short* __restrict__ xnt,
                                                       const unsigned short* __restrict__ wn,
                                                       const float* __restrict__ invn,
                                                       const float* __restrict__ ck,
                                                       unsigned short* __restrict__ act,
                                                       float* __restrict__ bgacc) {
    int ft = blockIdx.x, pt = blockIdx.y;
    int tid = threadIdx.x, lane = tid & 63, w = tid >> 6;
    int wm = w & 1, wq = w >> 1;
    __shared__ __align__(16) unsigned short a_lds[128 * 64];
    __shared__ __align__(16) unsigned short b_lds[128 * 64];
    __shared__ float ck_l[NCL_ * KF_];
    __shared__ float inv_l[128];
    __shared__ float bga_l[128 * NCL_];

    for (int i = tid; i < NCL_ * KF_; i += 256) ck_l[i] = ck[i];
    if (tid < 128) inv_l[tid] = invn[(size_t)pt * 128 + tid];
    for (int i = tid; i < 128 * NCL_; i += 256) bga_l[i] = 0.f;

    const unsigned short* ga = wn + ((size_t)(ft * 128) + (tid >> 3)) * 512 + (tid & 7) * 8;
    const unsigned short* gb = xnt + ((size_t)pt * 128 + (tid >> 3)) * 512 + (tid & 7) * 8;
    unsigned short* la = a_lds + (tid >> 3) * 64 + (tid & 7) * 8;
    unsigned short* lb = b_lds + (tid >> 3) * 64 + (tid & 7) * 8;

    floatx4 acc[4][4] = {};
    for (int ks = 0; ks < 8; ++ks) {
#pragma unroll
        for (int s = 0; s < 4; ++s) {
            gl2lds16(ga + (size_t)s * 32 * 512 + ks * 64, la + s * 32 * 64);
            gl2lds16(gb + (size_t)s * 32 * 512 + ks * 64, lb + s * 32 * 64);
        }
        __syncthreads();
#pragma unroll
        for (int k2 = 0; k2 < 2; ++k2) {
            short8 af[4], bf[4];
#pragma unroll
            for (int i = 0; i < 4; ++i) {
                af[i] = *(const short8*)&a_lds[(wm * 64 + i * 16 + (lane & 15)) * 64 + k2 * 32 + (lane >> 4) * 8];
                bf[i] = *(const short8*)&b_lds[(wq * 64 + i * 16 + (lane & 15)) * 64 + k2 * 32 + (lane >> 4) * 8];
            }
#pragma unroll
            for (int mi = 0; mi < 4; ++mi)
#pragma unroll
                for (int ni = 0; ni < 4; ++ni)
                    acc[mi][ni] = __builtin_amdgcn_mfma_f32_16x16x32_bf16(af[mi], bf[ni], acc[mi][ni], 0, 0, 0);
        }
        __syncthreads();
    }

#pragma unroll
    for (int ni = 0; ni < 4; ++ni) {
        int px_l = wq * 64 + ni * 16 + (lane & 15);
        float inv = inv_l[px_l];
        size_t row_g = (size_t)pt * 128 + px_l;
        float bp[NCL_] = {0.f, 0.f, 0.f, 0.f, 0.f};
#pragma unroll
        for (int mi = 0; mi < 4; ++mi) {
            int f_g = ft * 128 + wm * 64 + mi * 16 + (lane >> 4) * 4;
            int chn = ft * 8 + wm * 4 + mi;      // f_g >> 4
            int kin = (lane >> 4) * 4;           // within 16k chunk
            short4v pk;
            float av[4];
#pragma unroll
            for (int r = 0; r < 4; ++r) {
                float cv = acc[mi][ni][r] * inv;
                float a = cv > 0.f ? __expf(30.f * cv) : 0.f;
                av[r] = a;
                pk[r] = (short)f2bf(a);
            }
            *(short4v*)(act + ((size_t)chn * 100352 + row_g) * 16 + kin) = pk;
#pragma unroll
            for (int n = 0; n < NCL_; ++n)
                bp[n] += av[0] * ck_l[n * KF_ + f_g] + av[1] * ck_l[n * KF_ + f_g + 1] +
                         av[2] * ck_l[n * KF_ + f_g + 2] + av[3] * ck_l[n * KF_ + f_g + 3];
        }
#pragma unroll
        for (int n = 0; n < NCL_; ++n) {
            float v = bp[n];
            v += __shfl_xor(v, 16);
            v += __shfl_xor(v, 32);
            if ((lane >> 4) == 0) atomicAdd(&bga_l[px_l * NCL_ + n], v);
        }
    }
    __syncthreads();
    if (tid < 128) {
        size_t row_g = (size_t)pt * 128 + tid;
#pragma unroll
        for (int n = 0; n < NCL_; ++n)
            atomicAdd(&bgacc[row_g * 8 + n], bga_l[tid * NCL_ + n]);
    }
}

// ---- K4: single-pass fg, async global_load_lds 2-phase pipeline.
// 196 blocks x 1024 thr (16 waves, 1 px each). K in 32 stages of 16.
// LDS per buffer: mm [48m][1044B pad] dense [k16][px16] fp32; act [16 instr][1040B].
#define MMBUF 50112      // 48*1044
#define ACTBUF 16640     // 16*1040
#define OFF_ACT0 (2*MMBUF)
#define OFF_CSUM (2*MMBUF + 2*ACTBUF)
#define OFF_PMS  (OFF_CSUM + 3072)
#define OFF_BGS  (OFF_PMS + 6144)
__global__ __launch_bounds__(1024) void fg_kernel(const unsigned short* __restrict__ act,
                                                  const float* __restrict__ mm,
                                                  const float* __restrict__ bgacc,
                                                  float* __restrict__ pm) {
    __shared__ __align__(16) unsigned char L[OFF_BGS + 2048];
    float* csum_s = (float*)(L + OFF_CSUM);   // [48][16]
    float* pms    = (float*)(L + OFF_PMS);    // [48][32]
    float* bgs    = (float*)(L + OFF_BGS);    // [32][16]

    int p0 = blockIdx.x * 16;
    int tid = threadIdx.x;
    int lane = tid & 63, wid = tid >> 6;      // wave = pixel pp
    int li = lane & 15, q = lane >> 4;
    int pp = wid;
    int w3 = wid * 3;

    for (int i = tid; i < 1536; i += 1024) pms[i] = 0.f;
    if (tid < 512) {
        int b = tid >> 4, px = tid & 15;
        const float* bga = bgacc + ((size_t)b * HW_ + p0 + px) * 8;
        float mx = -1e30f;
#pragma unroll
        for (int n = 0; n < NCL_; ++n) mx = fmaxf(mx, logf(bga[n] * 0.6f + 1e-10f));
        bgs[tid] = mx;
    }

    // per-lane global source bases
    const float* mm_src = mm + ((size_t)(w3 * KF_) + (size_t)(lane >> 4)) * HW_ + p0 + (lane & 15);
    const unsigned short* act_src = act +
        ((size_t)(2 * wid + (lane >> 5)) * HW_ + p0 + ((lane >> 1) & 15)) * 16 + (lane & 1) * 8;

    auto stage = [&](int s) {
        unsigned char* mb = L + (s & 1) * MMBUF;
        unsigned char* ab = L + OFF_ACT0 + (s & 1) * ACTBUF;
        const float* ms = mm_src + (size_t)s * 16 * HW_;
#pragma unroll
        for (int jj = 0; jj < 12; ++jj)
            gl2lds4(ms + (size_t)((jj >> 2) * KF_ + (jj & 3) * 4) * HW_,
                    mb + (w3 + (jj >> 2)) * 1044 + (jj & 3) * 256);
        gl2lds16(act_src + (size_t)s * 100352 * 16, ab + wid * 1040);
    };

    short8 fa[2] = {};
    short8 fmA[3] = {};
    floatx4 acc[3][2] = {};
    float csp[3] = {0.f, 0.f, 0.f};

    stage(0);
    __syncthreads();

#pragma unroll 2
    for (int s = 0; s < 32; ++s) {
        if (s < 31) stage(s + 1);
        const unsigned char* mc = L + (s & 1) * MMBUF;
        const unsigned char* ac = L + OFF_ACT0 + (s & 1) * ACTBUF;
        if ((q >> 1) == (s & 1)) {
            // B fragments (act, bf16): 2 x ds_read_b128
#pragma unroll
            for (int bf = 0; bf < 2; ++bf)
                fa[bf] = *(const short8*)(ac + (bf * 8 + (li >> 1)) * 1040 +
                                          ((li & 1) * 16 + pp) * 32 + (q & 1) * 16);
            // A fragments (mm, fp32 -> clip -> csum -> bf16)
#pragma unroll
            for (int mf = 0; mf < 3; ++mf) {
                const unsigned char* arow = mc + (mf * 16 + li) * 1044 + (q & 1) * 512 + pp * 4;
                short8 pk;
                float s0 = 0.f;
#pragma unroll
                for (int j = 0; j < 8; ++j) {
                    float x = *(const float*)(arow + j * 64);
                    x = fminf(fmaxf(x, 0.f), 1.f);
                    s0 += x;
                    pk[j] = (short)f2bf(x);
                }
                csp[mf] += s0;
                fmA[mf] = pk;
            }
        }
        if (s & 1) {
#pragma unroll
            for (int mf = 0; mf < 3; ++mf) {
                acc[mf][0] = __builtin_amdgcn_mfma_f32_16x16x32_bf16(fmA[mf], fa[0], acc[mf][0], 0, 0, 0);
                acc[mf][1] = __builtin_amdgcn_mfma_f32_16x16x32_bf16(fmA[mf], fa[1], acc[mf][1], 0, 0, 0);
            }
        }
        __syncthreads();
    }

    // csum: reduce over the 4 q-lanes holding (m, pp) partials
#pragma unroll
    for (int mf = 0; mf < 3; ++mf) {
        float v = csp[mf];
        v += __shfl_xor(v, 16);
        v += __shfl_xor(v, 32);
        if (q == 0) csum_s[(mf * 16 + li) * 16 + pp] = v;
    }
    __syncthreads();

    // epilogue: log, bg-max, per-(m,b) pixel sum
#pragma unroll
    for (int mf = 0; mf < 3; ++mf)
#pragma unroll
        for (int bf = 0; bf < 2; ++bf) {
            int b = bf * 16 + li;
            float bgv = bgs[b * 16 + pp];
#pragma unroll
            for (int r = 0; r < 4; ++r) {
                int m = mf * 16 + q * 4 + r;
                float inv = 1.f / fmaxf(csum_s[m * 16 + pp], 1e-12f);
                float v = fmaxf(logf(acc[mf][bf][r] * inv * 0.4f + 1e-10f), bgv);
                atomicAdd(&pms[m * 32 + b], v);
            }
        }
    __syncthreads();
    if (tid < 512) {
        int i3 = tid * 3;
#pragma unroll
        for (int j = 0; j < 3; ++j) {
            int i = i3 + j;
            int m = i >> 5, b = i & 31;
            atomicAdd(&pm[(size_t)b * KM_ + m], pms[i]);
        }
    }
}

// ---- K5: scores -> mix_likeli -> softmax
__global__ __launch_bounds__(64) void final_kernel(const float* __restrict__ pm,
                                                   float* __restrict__ out_soft,
                                                   float* __restrict__ out_ml) {
    int b = threadIdx.x;
    if (b >= B_) return;
    float ml[12];
#pragma unroll
    for (int c = 0; c < 12; ++c) {
        float s = -1e30f;
#pragma unroll
        for (int j = 0; j < 4; ++j) s = fmaxf(s, pm[(size_t)b * KM_ + c * 4 + j]);
        ml[c] = s / (float)HW_;
    }
    float z[12], zs = 0.f;
#pragma unroll
    for (int c = 0; c < 12; ++c) {
        float e = fminf(fmaxf(ml[c] * 2.f, -88.7f), 88.7f);
        z[c] = expf(e); zs += z[c];
    }
#pragma unroll
    for (int c = 0; c < 12; ++c) {
        out_soft[(size_t)b * 12 + c] = z[c] / zs;
        out_ml[(size_t)b * 12 + c] = ml[c];
    }
}

extern "C" void kernel_launch(void* const* d_in, const int* in_sizes, int n_in,
                              void* d_out, int out_size, void* d_ws, size_t ws_size,
                              hipStream_t stream) {
    const float* vgg = (const float*)d_in[0];
    const float* cw  = (const float*)d_in[1];
    const float* mmp = (const float*)d_in[2];
    const float* cl  = (const float*)d_in[3];
    float* out = (float*)d_out;
    char* ws = (char*)d_ws;

    unsigned short* wn   = (unsigned short*)(ws);              // 524288 B
    float* ck            = (float*)(ws + 524288);              // 10240 B
    float* invn          = (float*)(ws + 534528);              // 401408 B
    float* pm            = (float*)(ws + 935936);              // 6144 B
    float* bgacc         = (float*)(ws + 942080);              // 3211264 B
    unsigned short* xnt  = (unsigned short*)(ws + 4153344);    // 102760448 B
    const size_t ACT_OFF = 4153344 + 102760448;                // 106913792
    const size_t ACT_BYTES = (size_t)B_ * HW_ * KF_ * 2;       // 102760448

    int big_ws = (ws_size >= ACT_OFF + ACT_BYTES) ? 1 : 0;
    unsigned short* act = big_ws ? (unsigned short*)(ws + ACT_OFF)
                                 : (unsigned short*)(out + 384);

    hipMemsetAsync(pm, 0, (size_t)B_ * KM_ * sizeof(float), stream);
    hipMemsetAsync(bgacc, 0, (size_t)B_ * HW_ * 8 * sizeof(float), stream);
    prep_kernel<<<dim3(KF_ + NCL_), dim3(64), 0, stream>>>(cw, cl, wn, ck);
    xprep_kernel<<<dim3(49, 32), dim3(512), 0, stream>>>(vgg, xnt, invn, out + 384, big_ws);
    gemm_act_kernel<<<dim3(4, 784), dim3(256), 0, stream>>>(xnt, wn, invn, ck, act, bgacc);
    fg_kernel<<<dim3(196), dim3(1024), 0, stream>>>(act, mmp, bgacc, pm);
    final_kernel<<<1, 64, 0, stream>>>(pm, out, out + 384 + (size_t)B_ * C_ * HW_);
    if (!big_ws)
        hipMemcpyAsync(out + 384, vgg, (size_t)B_ * C_ * HW_ * sizeof(float),
                       hipMemcpyDeviceToDevice, stream);
}

// Round 7
// 405.870 us; speedup vs baseline: 1.2476x; 1.1572x over previous
//
#include <hip/hip_runtime.h>

#define B_ 32
#define C_ 512
#define HW_ 3136
#define KF_ 512
#define KM_ 48
#define NCL_ 5

typedef __attribute__((ext_vector_type(8))) short short8;
typedef __attribute__((ext_vector_type(4))) short short4v;
typedef __attribute__((ext_vector_type(4))) float floatx4;
typedef unsigned int u32;
typedef u32 __attribute__((address_space(1))) gu32;
typedef u32 __attribute__((address_space(3))) lu32;

__device__ __forceinline__ unsigned short f2bf(float f) {
    union { float f; unsigned u; } v; v.f = f;
    unsigned r = v.u + 0x7FFFu + ((v.u >> 16) & 1u);
    return (unsigned short)(r >> 16);
}
__device__ __forceinline__ float bf2f(unsigned short u) {
    union { unsigned u; float f; } v; v.u = ((unsigned)u) << 16;
    return v.f;
}
__device__ __forceinline__ void gl2lds16(const void* g, void* l) {
    __builtin_amdgcn_global_load_lds((const gu32*)g, (lu32*)l, 16, 0, 0);
}
__device__ __forceinline__ void gl2lds4(const void* g, void* l) {
    __builtin_amdgcn_global_load_lds((const gu32*)g, (lu32*)l, 4, 0, 0);
}

// ---- K0: normalize conv weights -> bf16 wn; clutter -> ckb (clip + L1, bf16,
//      padded to 16 rows, rows >= NCL_ zeroed)
__global__ __launch_bounds__(64) void prep_kernel(const float* __restrict__ w,
                                                  const float* __restrict__ cl,
                                                  unsigned short* __restrict__ wn,
                                                  unsigned short* __restrict__ ckb) {
    int bid = blockIdx.x, t = threadIdx.x;
    if (bid < KF_) {
        const float* row = w + (size_t)bid * C_;
        float ss = 0.f;
        float x[8];
#pragma unroll
        for (int j = 0; j < 8; ++j) { x[j] = row[t * 8 + j]; ss += x[j] * x[j]; }
        for (int m = 32; m >= 1; m >>= 1) ss += __shfl_xor(ss, m);
        float inv = 1.f / sqrtf(ss);
#pragma unroll
        for (int j = 0; j < 8; ++j) wn[(size_t)bid * C_ + t * 8 + j] = f2bf(x[j] * inv);
    } else {
        int n = bid - KF_;                 // 0..15
        if (n >= 16) return;
        if (n < NCL_) {
            const float* row = cl + (size_t)n * KF_;
            float s = 0.f;
            float v[8];
#pragma unroll
            for (int j = 0; j < 8; ++j) {
                float x = row[t * 8 + j];
                x = fminf(fmaxf(x, 0.f), 1.f);
                v[j] = x; s += x;
            }
            for (int m = 32; m >= 1; m >>= 1) s += __shfl_xor(s, m);
            float inv = 1.f / fmaxf(s, 1e-12f);
#pragma unroll
            for (int j = 0; j < 8; ++j) ckb[(size_t)n * KF_ + t * 8 + j] = f2bf(v[j] * inv);
        } else {
#pragma unroll
            for (int j = 0; j < 8; ++j) ckb[(size_t)n * KF_ + t * 8 + j] = 0;
        }
    }
}

// ---- K1: streaming pass: vgg -> xnt (raw bf16, [b*HW+p][c]), invn, vgg copy
__global__ __launch_bounds__(512) void xprep_kernel(const float* __restrict__ vgg,
                                                    unsigned short* __restrict__ xnt,
                                                    float* __restrict__ invn,
                                                    float* __restrict__ out_vgg,
                                                    int write_vgg) {
    int pt = blockIdx.x, b = blockIdx.y;
    int tid = threadIdx.x;
    int px = tid & 63, cq = tid >> 6;
    __shared__ __align__(16) unsigned short tile[64][512];
    __shared__ float ssp[8][64];
    const float* vcol = vgg + (size_t)b * C_ * HW_ + pt * 64 + px;
    float* ovcol = out_vgg + (size_t)b * C_ * HW_ + pt * 64 + px;

    float ss = 0.f;
#pragma unroll
    for (int j = 0; j < 16; ++j) {
        int c0 = cq * 64 + j * 4;
        float x0 = vcol[(size_t)(c0 + 0) * HW_];
        float x1 = vcol[(size_t)(c0 + 1) * HW_];
        float x2 = vcol[(size_t)(c0 + 2) * HW_];
        float x3 = vcol[(size_t)(c0 + 3) * HW_];
        ss += x0 * x0 + x1 * x1 + x2 * x2 + x3 * x3;
        short4v pk;
        pk[0] = (short)f2bf(x0); pk[1] = (short)f2bf(x1);
        pk[2] = (short)f2bf(x2); pk[3] = (short)f2bf(x3);
        *(short4v*)&tile[px][c0] = pk;
        if (write_vgg) {
            ovcol[(size_t)(c0 + 0) * HW_] = x0;
            ovcol[(size_t)(c0 + 1) * HW_] = x1;
            ovcol[(size_t)(c0 + 2) * HW_] = x2;
            ovcol[(size_t)(c0 + 3) * HW_] = x3;
        }
    }
    ssp[cq][px] = ss;
    __syncthreads();
    if (tid < 64) {
        float s = 0.f;
#pragma unroll
        for (int q = 0; q < 8; ++q) s += ssp[q][tid];
        float n = sqrtf(s);
        invn[(size_t)b * HW_ + pt * 64 + tid] = (n == 0.f) ? 1.f : 1.f / n;
    }
    __syncthreads();
    int row = tid >> 3, ch = tid & 7;
    unsigned short* orow = xnt + ((size_t)b * HW_ + pt * 64 + row) * 512;
#pragma unroll
    for (int j = 0; j < 8; ++j) {
        int c8 = (ch + 8 * j) * 8;
        *(short8*)(orow + c8) = *(const short8*)&tile[row][c8];
    }
}

// ---- K2: pure GEMM act = exp(30 * (xnt . wn) * invn), stage-ahead dbuf.
// 3136 linear blocks, XCD-bijective swizzle; decode pt (784) x ft (4), ft
// adjacent within an XCD so the xnt tile is read 4x from one L2.
// act written in 16k chunks: act[(chn*100352 + row)*16 + kin], chn = f>>4.
__global__ __launch_bounds__(512) void gemm_act_kernel(const unsigned short* __restrict__ xnt,
                                                       const unsigned short* __restrict__ wn,
                                                       const float* __restrict__ invn,
                                                       unsigned short* __restrict__ act) {
    int wg = blockIdx.x;
    int swz = (wg & 7) * 392 + (wg >> 3);   // 3136 = 8*392, bijective
    int pt = swz >> 2, ft = swz & 3;
    int tid = threadIdx.x, lane = tid & 63;
    int wid = tid >> 6;
    int li = lane & 15, q = lane >> 4;
    int wm = wid & 1, wq = wid >> 1;        // M-half(64f) x N-quarter(32px)

    __shared__ __align__(16) unsigned short a_lds[2][128 * 64];
    __shared__ __align__(16) unsigned short b_lds[2][128 * 64];
    __shared__ float inv_l[128];
    if (tid < 128) inv_l[tid] = invn[(size_t)pt * 128 + tid];

    const unsigned short* ga = wn + ((size_t)ft * 128 + (tid >> 3)) * 512 + (tid & 7) * 8;
    const unsigned short* gb = xnt + ((size_t)pt * 128 + (tid >> 3)) * 512 + (tid & 7) * 8;
    int ldst = tid * 8;   // shorts; per-wave linear (lane*16B) as gl2lds requires

    floatx4 acc[4][2] = {};

    // stage(0)
#pragma unroll
    for (int i = 0; i < 2; ++i) {
        gl2lds16(ga + (size_t)i * 64 * 512, &a_lds[0][ldst + i * 4096]);
        gl2lds16(gb + (size_t)i * 64 * 512, &b_lds[0][ldst + i * 4096]);
    }
    __syncthreads();

#pragma unroll 1
    for (int s = 0; s < 8; ++s) {
        if (s < 7) {
            int nb = (s + 1) & 1;
#pragma unroll
            for (int i = 0; i < 2; ++i) {
                gl2lds16(ga + (size_t)i * 64 * 512 + (s + 1) * 64, &a_lds[nb][ldst + i * 4096]);
                gl2lds16(gb + (size_t)i * 64 * 512 + (s + 1) * 64, &b_lds[nb][ldst + i * 4096]);
            }
        }
        int buf = s & 1;
#pragma unroll
        for (int k2 = 0; k2 < 2; ++k2) {
            short8 af[4], bfr[2];
#pragma unroll
            for (int i = 0; i < 4; ++i)
                af[i] = *(const short8*)&a_lds[buf][(wm * 64 + i * 16 + li) * 64 + k2 * 32 + q * 8];
#pragma unroll
            for (int j = 0; j < 2; ++j)
                bfr[j] = *(const short8*)&b_lds[buf][(wq * 32 + j * 16 + li) * 64 + k2 * 32 + q * 8];
#pragma unroll
            for (int i = 0; i < 4; ++i)
#pragma unroll
                for (int j = 0; j < 2; ++j)
                    acc[i][j] = __builtin_amdgcn_mfma_f32_16x16x32_bf16(af[i], bfr[j], acc[i][j], 0, 0, 0);
        }
        __syncthreads();
    }

    // epilogue: scale, exp, pack, store
#pragma unroll
    for (int j = 0; j < 2; ++j) {
        int px = wq * 32 + j * 16 + li;
        float inv = inv_l[px];
        size_t row_g = (size_t)pt * 128 + px;
#pragma unroll
        for (int i = 0; i < 4; ++i) {
            int chn = ft * 8 + wm * 4 + i;
            short4v pk;
#pragma unroll
            for (int r = 0; r < 4; ++r) {
                float cv = acc[i][j][r] * inv;
                float a = cv > 0.f ? __expf(30.f * cv) : 0.f;
                pk[r] = (short)f2bf(a);
            }
            *(short4v*)(act + ((size_t)chn * 100352 + row_g) * 16 + q * 4) = pk;
        }
    }
}

// ---- K4: single-pass fg + fused bg (ck as extra MFMA A-operand).
// 196 blocks x 1024 thr (16 waves, 1 px each). K in 32 stages of 16.
#define MMBUF 50112      // 48*1044
#define ACTBUF 16640     // 16*1040
#define OFF_ACT0 (2*MMBUF)
#define OFF_CSUM (2*MMBUF + 2*ACTBUF)
#define OFF_PMS  (OFF_CSUM + 3072)
#define OFF_CKB  (OFF_PMS + 6144)
__global__ __launch_bounds__(1024) void fg_kernel(const unsigned short* __restrict__ act,
                                                  const float* __restrict__ mm,
                                                  const unsigned short* __restrict__ ckb,
                                                  float* __restrict__ pm) {
    __shared__ __align__(16) unsigned char L[OFF_CKB + 16 * 520 * 2];
    float* csum_s = (float*)(L + OFF_CSUM);           // [48][16]
    float* pms    = (float*)(L + OFF_PMS);            // [48][32]
    unsigned short* ckbl = (unsigned short*)(L + OFF_CKB);  // [16][520]

    int p0 = blockIdx.x * 16;
    int tid = threadIdx.x;
    int lane = tid & 63, wid = tid >> 6;      // wave = pixel pp
    int li = lane & 15, q = lane >> 4;
    int pp = wid;
    int w3 = wid * 3;

    for (int i = tid; i < 1536; i += 1024) pms[i] = 0.f;
    {   // ckb -> LDS (padded rows of 520 shorts)
        int row = tid >> 6, cg = tid & 63;
        *(short8*)&ckbl[row * 520 + cg * 8] = *(const short8*)(ckb + row * 512 + cg * 8);
    }

    // per-lane global source bases
    const float* mm_src = mm + ((size_t)(w3 * KF_) + (size_t)(lane >> 4)) * HW_ + p0 + (lane & 15);
    const unsigned short* act_src = act +
        ((size_t)(2 * wid + (lane >> 5)) * HW_ + p0 + ((lane >> 1) & 15)) * 16 + (lane & 1) * 8;

    auto stage = [&](int s) {
        unsigned char* mb = L + (s & 1) * MMBUF;
        unsigned char* ab = L + OFF_ACT0 + (s & 1) * ACTBUF;
        const float* ms = mm_src + (size_t)s * 16 * HW_;
#pragma unroll
        for (int jj = 0; jj < 12; ++jj)
            gl2lds4(ms + (size_t)((jj >> 2) * KF_ + (jj & 3) * 4) * HW_,
                    mb + (w3 + (jj >> 2)) * 1044 + (jj & 3) * 256);
        gl2lds16(act_src + (size_t)s * 100352 * 16, ab + wid * 1040);
    };

    short8 fa[2] = {};
    short8 fmA[3] = {};
    short8 fck = {};
    floatx4 acc[3][2] = {};
    floatx4 accbg[2] = {};
    float csp[3] = {0.f, 0.f, 0.f};

    stage(0);
    __syncthreads();

#pragma unroll 2
    for (int s = 0; s < 32; ++s) {
        if (s < 31) stage(s + 1);
        const unsigned char* mc = L + (s & 1) * MMBUF;
        const unsigned char* ac = L + OFF_ACT0 + (s & 1) * ACTBUF;
        if ((q >> 1) == (s & 1)) {
            // B fragments (act, bf16)
#pragma unroll
            for (int bf = 0; bf < 2; ++bf)
                fa[bf] = *(const short8*)(ac + (bf * 8 + (li >> 1)) * 1040 +
                                          ((li & 1) * 16 + pp) * 32 + (q & 1) * 16);
            // A fragments (mm, fp32 -> clip -> csum -> bf16)
#pragma unroll
            for (int mf = 0; mf < 3; ++mf) {
                const unsigned char* arow = mc + (mf * 16 + li) * 1044 + (q & 1) * 512 + pp * 4;
                short8 pk;
                float s0 = 0.f;
#pragma unroll
                for (int j = 0; j < 8; ++j) {
                    float x = *(const float*)(arow + j * 64);
                    x = fminf(fmaxf(x, 0.f), 1.f);
                    s0 += x;
                    pk[j] = (short)f2bf(x);
                }
                csp[mf] += s0;
                fmA[mf] = pk;
            }
            // ck fragment (same k positions as fmA)
            fck = *(const short8*)&ckbl[li * 520 + s * 16 + (q & 1) * 8];
        }
        if (s & 1) {
#pragma unroll
            for (int mf = 0; mf < 3; ++mf) {
                acc[mf][0] = __builtin_amdgcn_mfma_f32_16x16x32_bf16(fmA[mf], fa[0], acc[mf][0], 0, 0, 0);
                acc[mf][1] = __builtin_amdgcn_mfma_f32_16x16x32_bf16(fmA[mf], fa[1], acc[mf][1], 0, 0, 0);
            }
            accbg[0] = __builtin_amdgcn_mfma_f32_16x16x32_bf16(fck, fa[0], accbg[0], 0, 0, 0);
            accbg[1] = __builtin_amdgcn_mfma_f32_16x16x32_bf16(fck, fa[1], accbg[1], 0, 0, 0);
        }
        __syncthreads();
    }

    // csum: reduce over the 4 q-lanes holding (m, pp) partials
#pragma unroll
    for (int mf = 0; mf < 3; ++mf) {
        float v = csp[mf];
        v += __shfl_xor(v, 16);
        v += __shfl_xor(v, 32);
        if (q == 0) csum_s[(mf * 16 + li) * 16 + pp] = v;
    }

    // bg: rows n = q*4+r (zero-padded rows give log(1e-10), a safe lower bound)
    float bgv[2];
#pragma unroll
    for (int bf = 0; bf < 2; ++bf) {
        float v = -1e30f;
#pragma unroll
        for (int r = 0; r < 4; ++r) v = fmaxf(v, logf(accbg[bf][r] * 0.6f + 1e-10f));
        v = fmaxf(v, __shfl_xor(v, 16));
        v = fmaxf(v, __shfl_xor(v, 32));
        bgv[bf] = v;
    }
    __syncthreads();

    // epilogue: log, bg-max, per-(m,b) pixel sum
#pragma unroll
    for (int mf = 0; mf < 3; ++mf)
#pragma unroll
        for (int bf = 0; bf < 2; ++bf) {
            int b = bf * 16 + li;
#pragma unroll
            for (int r = 0; r < 4; ++r) {
                int m = mf * 16 + q * 4 + r;
                float inv = 1.f / fmaxf(csum_s[m * 16 + pp], 1e-12f);
                float v = fmaxf(logf(acc[mf][bf][r] * inv * 0.4f + 1e-10f), bgv[bf]);
                atomicAdd(&pms[m * 32 + b], v);
            }
        }
    __syncthreads();
    if (tid < 512) {
        int i3 = tid * 3;
#pragma unroll
        for (int j = 0; j < 3; ++j) {
            int i = i3 + j;
            int m = i >> 5, b = i & 31;
            atomicAdd(&pm[(size_t)b * KM_ + m], pms[i]);
        }
    }
}

// ---- K5: scores -> mix_likeli -> softmax
__global__ __launch_bounds__(64) void final_kernel(const float* __restrict__ pm,
                                                   float* __restrict__ out_soft,
                                                   float* __restrict__ out_ml) {
    int b = threadIdx.x;
    if (b >= B_) return;
    float ml[12];
#pragma unroll
    for (int c = 0; c < 12; ++c) {
        float s = -1e30f;
#pragma unroll
        for (int j = 0; j < 4; ++j) s = fmaxf(s, pm[(size_t)b * KM_ + c * 4 + j]);
        ml[c] = s / (float)HW_;
    }
    float z[12], zs = 0.f;
#pragma unroll
    for (int c = 0; c < 12; ++c) {
        float e = fminf(fmaxf(ml[c] * 2.f, -88.7f), 88.7f);
        z[c] = expf(e); zs += z[c];
    }
#pragma unroll
    for (int c = 0; c < 12; ++c) {
        out_soft[(size_t)b * 12 + c] = z[c] / zs;
        out_ml[(size_t)b * 12 + c] = ml[c];
    }
}

extern "C" void kernel_launch(void* const* d_in, const int* in_sizes, int n_in,
                              void* d_out, int out_size, void* d_ws, size_t ws_size,
                              hipStream_t stream) {
    const float* vgg = (const float*)d_in[0];
    const float* cw  = (const float*)d_in[1];
    const float* mmp = (const float*)d_in[2];
    const float* cl  = (const float*)d_in[3];
    float* out = (float*)d_out;
    char* ws = (char*)d_ws;

    unsigned short* wn   = (unsigned short*)(ws);              // 524288 B
    unsigned short* ckb  = (unsigned short*)(ws + 524288);     // 16384 B
    float* invn          = (float*)(ws + 540672);              // 401408 B
    float* pm            = (float*)(ws + 942080);              // 6144 B
    unsigned short* xnt  = (unsigned short*)(ws + 948224);     // 102760448 B
    const size_t ACT_OFF = 948224 + 102760448;                 // 103708672
    const size_t ACT_BYTES = (size_t)B_ * HW_ * KF_ * 2;       // 102760448

    int big_ws = (ws_size >= ACT_OFF + ACT_BYTES) ? 1 : 0;
    unsigned short* act = big_ws ? (unsigned short*)(ws + ACT_OFF)
                                 : (unsigned short*)(out + 384);

    hipMemsetAsync(pm, 0, (size_t)B_ * KM_ * sizeof(float), stream);
    prep_kernel<<<dim3(KF_ + 16), dim3(64), 0, stream>>>(cw, cl, wn, ckb);
    xprep_kernel<<<dim3(49, 32), dim3(512), 0, stream>>>(vgg, xnt, invn, out + 384, big_ws);
    gemm_act_kernel<<<dim3(3136), dim3(512), 0, stream>>>(xnt, wn, invn, act);
    fg_kernel<<<dim3(196), dim3(1024), 0, stream>>>(act, mmp, ckb, pm);
    final_kernel<<<1, 64, 0, stream>>>(pm, out, out + 384 + (size_t)B_ * C_ * HW_);
    if (!big_ws)
        hipMemcpyAsync(out + 384, vgg, (size_t)B_ * C_ * HW_ * sizeof(float),
                       hipMemcpyDeviceToDevice, stream);
}